// Round 10
// baseline (1099.525 us; speedup 1.0000x reference)
//
#include <hip/hip_runtime.h>
#include <math.h>

// B=256, T=2048, D=64, U=128, 4U=512, COND=32
namespace {
constexpr int kB    = 256;
constexpr int kT    = 2048;
constexpr int kD    = 64;
constexpr int kU    = 128;
constexpr int kCOND = 32;
constexpr int kCH   = 16;    // timesteps per x chunk
constexpr int kXGS  = 516;   // xg row stride in floats (R2/R8-measured: 0 conflicts)
}

typedef _Float16 f16x8 __attribute__((ext_vector_type(8)));
typedef float    f32x4 __attribute__((ext_vector_type(4)));

// VALU-diet activations (R8: -400 cyc/SIMD-step vs IEEE division expansion).
__device__ __forceinline__ float rcp_(float x) {
    return __builtin_amdgcn_rcpf(x);
}
__device__ __forceinline__ float sig_(float z) {
    return rcp_(1.0f + __expf(-z));
}
__device__ __forceinline__ float tanh_(float z) {
    const float e = __expf(-2.0f * fabsf(z));          // e = exp(-2|z|)
    const float t = 1.0f - 2.0f * e * rcp_(1.0f + e);  // (1-e)/(1+e)
    return copysignf(t, z);
}
// pin a 16B fragment so the allocator cannot rematerialize its global loads
__device__ __forceinline__ void pin4_(f16x8& w) {
    f32x4 t = __builtin_bit_cast(f32x4, w);
    asm volatile("" : "+v"(t));
    w = __builtin_bit_cast(f16x8, t);
}

// One WG (512 thr = 8 waves) per batch element, persistent over T steps.
// R9 ledger: step = 620 cyc MFMA pipe (32x 16x16x32 per SIMD, invariant)
// + ~620 cyc serial exchange (barrier-exit LDS burst -> read latency ->
// MFMA completion -> gates -> h-write -> barrier). R10 de-congests the
// barrier-exit critical path:
//  (a) xg acc-init pipelined ONE STEP AHEAD into registers: xg is
//      chunk-static (no RAW vs h), so the 4 b32 reads for step t+1 issue
//      right after step t's afh reads (latency buried under the 620-cyc
//      MFMA phase). Step-start LDS burst drops 8 -> 4 ops/wave; acc init
//      becomes a pure v_mov. (R7 did this WRONG: late reads + extra lgkm
//      drain; here reads are early and the barrier's lgkm(0) covers them.)
//  (b) explicit 2-body loop (t += 2): cur is a literal per body -> hbuf
//      addressing folds to immediate offsets.
// Everything else identical to R9: persistent acc + elem-0-only init,
// rcp-diet gates, all-wave xgemm spike at tin==8, swizzled 2-chunk x ring,
// lgkm-only barrier (never drains vmcnt).
__global__ __launch_bounds__(512, 2)
void lstm_mfma(const float* __restrict__ x,     // [B,T,D]
               const float* __restrict__ cond,  // [B,COND]
               const float* __restrict__ Wc,    // [COND,U]
               const float* __restrict__ bc,    // [U]
               const float* __restrict__ Wk,    // [D,4U]
               const float* __restrict__ Uk,    // [U,4U]
               const float* __restrict__ bias,  // [4U]
               float* __restrict__ out) {       // [B,U]
    const int b    = blockIdx.x;
    const int tid  = threadIdx.x;
    const int lane = tid & 63;
    const int w    = tid >> 6;     // wave 0..7
    const int q    = lane >> 4;    // quad 0..3
    const int c    = lane & 15;
    const int u    = 16 * w + c;   // this lane's state element

    __shared__ __align__(16) _Float16 hbuf[2][kU];        // h double-buffer
    __shared__ __align__(16) _Float16 xs[2][kCH * kD];    // x chunk (swizzled)
    __shared__ __align__(16) float    xg[2][kCH][kXGS];   // x@Wk + bias

    // ---- B-frags: 4 tiles x 6 K-chunks, k = 32*kc + 8*q + j, col = 16t + c ----
    // kc 0..1 = Wk (K=64), kc 2..5 = Uk (K=128)
    f16x8 wfrag[4][6];
    float btile[4];
    int   xcol[4];                 // this lane's xg columns
#pragma unroll
    for (int jt = 0; jt < 4; ++jt) {
        const int t   = w + 8 * jt;          // tile; jt = gate index (i,f,c~,o)
        const int col = 16 * t + c;
        xcol[jt] = col;
#pragma unroll
        for (int kc = 0; kc < 6; ++kc) {
            f16x8 f;
#pragma unroll
            for (int j = 0; j < 8; ++j) {
                const int k = 32 * kc + 8 * q + j;
                const float v = (k < kD) ? Wk[k * 512 + col]
                                         : Uk[(k - kD) * 512 + col];
                f[j] = (_Float16)v;
            }
            wfrag[jt][kc] = f;
        }
        btile[jt] = bias[col];
    }
#pragma unroll
    for (int jt = 0; jt < 4; ++jt)
#pragma unroll
        for (int kc = 0; kc < 6; ++kc) pin4_(wfrag[jt][kc]);

    // chunk-GEMM: xg[slot] = xs[slot] @ Wk + bias   (M = 16 timesteps)
    auto xgemm = [&](int slot) {
        f16x8 ax[2];
#pragma unroll
        for (int kc = 0; kc < 2; ++kc) {
            int byte = c * 128 + 64 * kc + 16 * q;
            byte ^= (c & 7) << 4;
            ax[kc] = *(const f16x8*)((const char*)&xs[slot][0] + byte);
        }
        f32x4 accx[4];
#pragma unroll
        for (int jt = 0; jt < 4; ++jt)
            accx[jt] = (f32x4){btile[jt], btile[jt], btile[jt], btile[jt]};
#pragma unroll
        for (int kc = 0; kc < 2; ++kc)
#pragma unroll
            for (int jt = 0; jt < 4; ++jt)
                accx[jt] = __builtin_amdgcn_mfma_f32_16x16x32_f16(
                    ax[kc], wfrag[jt][kc], accx[jt], 0, 0, 0);
#pragma unroll
        for (int jt = 0; jt < 4; ++jt) {
#pragma unroll
            for (int r = 0; r < 4; ++r)
                xg[slot][4 * q + r][xcol[jt]] = accx[jt][r];
        }
    };

    // ---- initial state: c0 = h0 = bc[u] + cond[b,:] @ Wc[:,u] ----
    float c_reg;
    {
        float a = bc[u];
        const float* cr = cond + b * kCOND;
#pragma unroll
        for (int kk = 0; kk < kCOND; ++kk) a = fmaf(cr[kk], Wc[kk * kU + u], a);
        c_reg = a;
        if (q == 0) hbuf[0][u] = (_Float16)a;
    }

    const float* xb = x + (size_t)b * kT * kD;

    // ---- stage chunk 0 (t = 0..15) into xs[0] (swizzled) ----
    {
        const int row = tid >> 5;            // timestep within chunk
        float2 v = *(const float2*)&xb[(size_t)row * kD + (tid & 31) * 2];
        int byte = row * 128 + (tid & 31) * 4;
        byte ^= (row & 7) << 4;
        _Float16* p = (_Float16*)((char*)&xs[0][0] + byte);
        p[0] = (_Float16)v.x;
        p[1] = (_Float16)v.y;
    }
    __syncthreads();
    xgemm(0);                 // xg[0] = chunk-0 preacts + bias
    __syncthreads();

    float  h_out = 0.0f;
    float2 xpf   = make_float2(0.0f, 0.0f);  // in-flight chunk prefetch
    f32x4  acc[4];                           // persistent; only [0] meaningful
#pragma unroll
    for (int jt = 0; jt < 4; ++jt)
        acc[jt] = (f32x4){0.0f, 0.0f, 0.0f, 0.0f};

    // step-0 acc-init pipelined into registers before the loop
    float xgn0[4], xgn1[4];
#pragma unroll
    for (int jt = 0; jt < 4; ++jt) xgn0[jt] = xg[0][0][xcol[jt]];

    // one LSTM step; cur is a compile-time literal at both call sites;
    // xgu = this step's acc-init (registers), xgl = next step's (loaded here)
    auto step = [&](int t, int cur, const float* xgu, float* xgl) {
        const int tin = t & (kCH - 1);
        const int csl = (t >> 4) & 1;

        // h A-frags: the only step-critical LDS reads (quad-broadcast)
        f16x8 afh[4];
#pragma unroll
        for (int kc = 0; kc < 4; ++kc)
            afh[kc] = *(const f16x8*)&hbuf[cur][32 * kc + 8 * q];

        // pipeline: next step's xg (chunk-static, no RAW vs h) -- latency
        // hides under this step's MFMA phase; barrier's lgkm(0) covers it
        {
            const int t1   = t + 1;
            const int csl1 = (t1 >> 4) & 1;
            const int tin1 = t1 & (kCH - 1);
            const float* src = &xg[csl1][tin1][0];
#pragma unroll
            for (int jt = 0; jt < 4; ++jt) xgl[jt] = src[xcol[jt]];
        }

        // issue next chunk's global loads (written to xs at tin==7)
        if (tin == 0) {
            int tr = t + kCH + (tid >> 5);
            if (tr > kT - 1) tr = kT - 1;    // tail clamp: staged, never read
            xpf = *(const float2*)&xb[(size_t)tr * kD + (tid & 31) * 2];
        }

        // acc init: element 0 only, pure v_mov from the pipelined register
#pragma unroll
        for (int jt = 0; jt < 4; ++jt) acc[jt][0] = xgu[jt];

#pragma unroll
        for (int kc = 0; kc < 4; ++kc)
#pragma unroll
            for (int jt = 0; jt < 4; ++jt)
                acc[jt] = __builtin_amdgcn_mfma_f32_16x16x32_f16(
                    afh[kc], wfrag[jt][2 + kc], acc[jt], 0, 0, 0);

        // gates: D is row-constant -> reg 0 of each tile = G[16t + c]
        const float iv = sig_(acc[0][0]);
        const float fv = sig_(acc[1][0]);
        const float cb = tanh_(acc[2][0]);
        const float ov = sig_(acc[3][0]);
        c_reg = fmaf(fv, c_reg, iv * cb);
        h_out = ov * tanh_(c_reg);

        if (q == 0) hbuf[cur ^ 1][u] = (_Float16)h_out;   // h_{t+1}

        // mid-chunk: land the prefetched x chunk into xs (swizzled)
        if (tin == 7) {
            const int row = tid >> 5;
            int byte = row * 128 + (tid & 31) * 4;
            byte ^= (row & 7) << 4;
            _Float16* p = (_Float16*)((char*)&xs[csl ^ 1][0] + byte);
            p[0] = (_Float16)xpf.x;
            p[1] = (_Float16)xpf.y;
        }
        // then run the dense chunk-GEMM for the next chunk's preacts
        if (tin == 8) xgemm(csl ^ 1);

        // LDS-only barrier: do NOT drain vmcnt -> prefetch stays in flight
        asm volatile("s_waitcnt lgkmcnt(0)\n\ts_barrier" ::: "memory");
    };

#pragma unroll 1
    for (int t = 0; t < kT; t += 2) {
        step(t,     0, xgn0, xgn1);   // even step: cur = 0 literal
        step(t + 1, 1, xgn1, xgn0);   // odd  step: cur = 1 literal
    }

    if (q == 0) out[b * kU + u] = h_out;
}

extern "C" void kernel_launch(void* const* d_in, const int* in_sizes, int n_in,
                              void* d_out, int out_size, void* d_ws, size_t ws_size,
                              hipStream_t stream) {
    const float* x    = (const float*)d_in[0];
    const float* cond = (const float*)d_in[1];
    const float* Wc   = (const float*)d_in[2];
    const float* bc   = (const float*)d_in[3];
    const float* Wk   = (const float*)d_in[4];
    const float* Uk   = (const float*)d_in[5];
    const float* b    = (const float*)d_in[6];
    float* out = (float*)d_out;

    lstm_mfma<<<dim3(kB), dim3(512), 0, stream>>>(x, cond, Wc, bc, Wk, Uk, b, out);
}